// Round 11
// baseline (418.123 us; speedup 1.0000x reference)
//
#include <hip/hip_runtime.h>
#include <math.h>

#define NB   8
#define NPTS 1024
#define PTS  8192      // NB*NPTS
#define KNN  16
#define PK   (PTS*KNN) // 131072

typedef __attribute__((ext_vector_type(8))) _Float16 f16x8;
typedef __attribute__((ext_vector_type(4))) float f32x4;

__device__ __forceinline__ unsigned short f2h(float f) {
  _Float16 h = (_Float16)f;
  union { _Float16 h; unsigned short u; } c; c.h = h;
  return c.u;
}
__device__ __forceinline__ float h2f(unsigned short u) {
  union { unsigned short u; _Float16 h; } c; c.u = u;
  return (float)c.h;
}

// ---------------- kNN: one WAVE per point; register-resident top-16, barrier-free ----------------
__global__ __launch_bounds__(256) void knn_kernel(const float* __restrict__ pos,
                                                  int* __restrict__ idx,
                                                  float* __restrict__ rel) {
  __shared__ float px[NPTS], py[NPTS], pz[NPTS];
  const int t = threadIdx.x;
  const int wv = t >> 6, lane = t & 63;
  const int b = blockIdx.x;
  const int graph = b >> 8;             // 256 blocks per graph
  const int base = graph << 10;
  for (int j = t; j < NPTS; j += 256) {
    px[j] = pos[3*(base+j)];
    py[j] = pos[3*(base+j)+1];
    pz[j] = pos[3*(base+j)+2];
  }
  __syncthreads();

  const int il = ((b & 255) << 2) + wv; // point index within graph
  const float pix = px[il], piy = py[il], piz = pz[il];
  const float sqi = pix*pix + piy*piy + piz*piz;

  float d[16];
  #pragma unroll
  for (int q = 0; q < 16; ++q) {
    const int j = (q << 6) + lane;
    const float x = px[j], y = py[j], z = pz[j];
    const float sqj = x*x + y*y + z*z;
    const float dt  = pix*x + piy*y + piz*z;
    d[q] = sqi + sqj - 2.0f*dt;
  }
  float mv = d[0]; int mq = 0;
  #pragma unroll
  for (int q = 1; q < 16; ++q) { if (d[q] < mv) { mv = d[q]; mq = q; } }

  int sel = 0;
  for (int s = 0; s < KNN; ++s) {
    float v = mv; int j = (mq << 6) + lane;
    #pragma unroll
    for (int m = 1; m <= 32; m <<= 1) {
      const float v2 = __shfl_xor(v, m);
      const int   j2 = __shfl_xor(j, m);
      if (v2 < v || (v2 == v && j2 < j)) { v = v2; j = j2; }
    }
    if (lane == s) sel = j;
    if (lane == (j & 63)) {
      const int wq = j >> 6;
      #pragma unroll
      for (int q = 0; q < 16; ++q) if (q == wq) d[q] = INFINITY;
      mv = d[0]; mq = 0;
      #pragma unroll
      for (int q = 1; q < 16; ++q) { if (d[q] < mv) { mv = d[q]; mq = q; } }
    }
  }

  if (lane < KNN) {
    const int i = base + il;
    const int r = i*KNN + lane;
    idx[r] = base + sel;
    rel[3*r]   = px[sel] - pix;
    rel[3*r+1] = py[sel] - piy;
    rel[3*r+2] = pz[sel] - piz;
  }
}

// ---------------- conv1 layer1 + fused BN partials; z1 stored fp16 ----------------
__global__ __launch_bounds__(256) void conv1_l1_kernel(const float* __restrict__ pos,
    const int* __restrict__ idx, const float* __restrict__ rel,
    const float* __restrict__ W1, const float* __restrict__ b1,
    unsigned short* __restrict__ z1h, float* __restrict__ partial) {
  const int r0 = blockIdx.x * 64;
  const int t = threadIdx.x;
  __shared__ float f[64][6];
  __shared__ float ls[256], ls2[256];
  if (t < 64) {
    const int r = r0 + t;
    const int j = idx[r];
    f[t][0] = pos[3*j]; f[t][1] = pos[3*j+1]; f[t][2] = pos[3*j+2];
    f[t][3] = rel[3*r]; f[t][4] = rel[3*r+1]; f[t][5] = rel[3*r+2];
  }
  __syncthreads();
  const int c = t & 63, rg = t >> 6;
  float w[6];
  #pragma unroll
  for (int q = 0; q < 6; ++q) w[q] = W1[q*64 + c];
  const float bb = b1[c];
  float s = 0.0f, s2 = 0.0f;
  for (int j = 0; j < 16; ++j) {
    const int lr = rg + 4*j;
    float z = bb;
    #pragma unroll
    for (int q = 0; q < 6; ++q) z += f[lr][q]*w[q];
    z1h[(size_t)(r0+lr)*64 + c] = f2h(z);
    s += z; s2 += z*z;
  }
  ls[t] = s; ls2[t] = s2;
  __syncthreads();
  if (t < 64) {
    float a = ls[t] + ls[t+64] + ls[t+128] + ls[t+192];
    float a2 = ls2[t] + ls2[t+64] + ls2[t+128] + ls2[t+192];
    partial[(size_t)blockIdx.x*128 + t]      = a;
    partial[(size_t)blockIdx.x*128 + 64 + t] = a2;
  }
}

// ---------------- sum rows of [R][128] -> mid[64][128] ----------------
__global__ __launch_bounds__(256) void sumcols128_kernel(const float* __restrict__ partial,
    int rowsPerBlock, float* __restrict__ mid) {
  const int b = blockIdx.x, t = threadIdx.x;
  const int c = t & 127, rh = t >> 7;
  float a = 0.0f;
  for (int r = rh; r < rowsPerBlock; r += 2)
    a += partial[(size_t)(b*rowsPerBlock + r)*128 + c];
  __shared__ float ls[256];
  ls[t] = a;
  __syncthreads();
  if (t < 128) mid[b*128 + t] = ls[t] + ls[t + 128];
}

__global__ __launch_bounds__(256) void stats_final_kernel(const float* __restrict__ partial,
    int G, int C, float invRows,
    const float* __restrict__ gamma, const float* __restrict__ beta,
    float* __restrict__ ss) {
  const int t = threadIdx.x;
  if (t >= C) return;
  float s = 0.0f, s2 = 0.0f;
  for (int g = 0; g < G; ++g) { s += partial[g*2*C + t]; s2 += partial[g*2*C + C + t]; }
  const float mu  = s * invRows;
  const float var = s2 * invRows - mu*mu;
  const float sc  = gamma[t] * rsqrtf(var + 1e-5f);
  ss[t] = sc; ss[C + t] = beta[t] - mu*sc;
}

// ---------------- conv1 layer2 + max: 4 points per block (one wave each), fp16 z1 ----------------
__global__ __launch_bounds__(256) void conv1_l2max_kernel(const unsigned short* __restrict__ z1h,
    const float* __restrict__ ss, const float* __restrict__ W2,
    const float* __restrict__ b2, float* __restrict__ x1) {
  __shared__ float h[4][KNN][64];
  const int wv = threadIdx.x >> 6, t = threadIdx.x & 63;
  const int i = blockIdx.x*4 + wv;
  const float sc = ss[t], sh = ss[64+t];
  #pragma unroll
  for (int k = 0; k < KNN; ++k) {
    const float z = h2f(z1h[(size_t)(i*KNN+k)*64 + t]);
    h[wv][k][t] = fmaxf(z*sc + sh, 0.0f);
  }
  __syncthreads();
  float w[64];
  #pragma unroll
  for (int d = 0; d < 64; ++d) w[d] = W2[d*64 + t];
  const float bb = b2[t];
  float acc = -INFINITY;
  for (int k = 0; k < KNN; ++k) {
    float y = bb;
    #pragma unroll
    for (int d = 0; d < 64; ++d) y += h[wv][k][d]*w[d];
    acc = fmaxf(acc, y);
  }
  x1[(size_t)i*64 + t] = acc;
}

// ---------------- conv2 layer1 + fused BN partials; za stored fp16 ----------------
__global__ __launch_bounds__(256) void conv2_l1_kernel(const float* __restrict__ x1,
    const int* __restrict__ idx, const float* __restrict__ rel,
    const float* __restrict__ W, const float* __restrict__ bias,
    unsigned short* __restrict__ zah, float* __restrict__ partial) {
  const int i = blockIdx.x;
  const int t = threadIdx.x;
  const int c = t & 63, kg = t >> 6;
  __shared__ float xg[KNN][64];
  __shared__ float rl[KNN][3];
  __shared__ float ls[256], ls2[256];
  #pragma unroll
  for (int j = 0; j < 4; ++j) {
    const int k = kg + 4*j;
    const int gj = idx[i*KNN + k];
    xg[k][c] = x1[(size_t)gj*64 + c];
  }
  if (t < KNN*3) rl[t/3][t%3] = rel[i*KNN*3 + t];
  __syncthreads();
  float w[67];
  #pragma unroll
  for (int q = 0; q < 67; ++q) w[q] = W[q*64 + c];
  const float bb = bias[c];
  float s = 0.0f, s2 = 0.0f;
  #pragma unroll
  for (int j = 0; j < 4; ++j) {
    const int k = kg + 4*j;
    float y = bb + rl[k][0]*w[64] + rl[k][1]*w[65] + rl[k][2]*w[66];
    #pragma unroll
    for (int q = 0; q < 64; ++q) y += xg[k][q]*w[q];
    zah[(size_t)(i*KNN+k)*64 + c] = f2h(y);
    s += y; s2 += y*y;
  }
  ls[t] = s; ls2[t] = s2;
  __syncthreads();
  if (t < 64) {
    float a = ls[t] + ls[t+64] + ls[t+128] + ls[t+192];
    float a2 = ls2[t] + ls2[t+64] + ls2[t+128] + ls2[t+192];
    partial[(size_t)i*128 + t]      = a;
    partial[(size_t)i*128 + 64 + t] = a2;
  }
}

// ---------------- W3 -> fp16 transposed [1024][128] ----------------
__global__ __launch_bounds__(256) void w3t_kernel(const float* __restrict__ W3,
                                                  unsigned short* __restrict__ W3T) {
  const int k = blockIdx.x;           // 0..127
  for (int n = threadIdx.x; n < 1024; n += 256)
    W3T[n*128 + k] = f2h(W3[(size_t)k*1024 + n]);
}

// ---------------- W2 -> fp16 transposed [128][64] ----------------
__global__ __launch_bounds__(256) void w2t_kernel(const float* __restrict__ W2,
                                                  unsigned short* __restrict__ W2T) {
  const int id0 = blockIdx.x*256 + threadIdx.x;
  const int stride = gridDim.x * 256;
  for (int id = id0; id < 128*64; id += stride) {
    const int n = id >> 6, k = id & 63;
    W2T[n*64 + k] = f2h(W2[k*128 + n]);
  }
}

// ---------------- conv2 layer2: fp16 MFMA + fused BN-stats; reads fp16 za, writes fp16 zb ----------------
__global__ __launch_bounds__(256) void conv2_l2_mfma(
    const unsigned short* __restrict__ zah, const float* __restrict__ ss,
    const unsigned short* __restrict__ W2T, const float* __restrict__ b2,
    unsigned short* __restrict__ zhb, float* __restrict__ partialB) {
  __shared__ unsigned short S[128*128];   // first 16KB: As; later: fp16 out tile
  __shared__ float ps[512];
  const int r0 = blockIdx.x * 128;
  const int t = threadIdx.x;
  const int lane = t & 63, w = t >> 6;
  const int quad = lane >> 4, mcol = lane & 15;

  // stage A: 128 rows x 64 ch, relu(bn) -> fp16, swizzled
  {
    const int kb = t & 7;
    const int rr = t >> 3;
    float sc[8], sh[8];
    #pragma unroll
    for (int q = 0; q < 8; ++q) { sc[q] = ss[kb*8 + q]; sh[q] = ss[64 + kb*8 + q]; }
    #pragma unroll
    for (int it = 0; it < 4; ++it) {
      const int r = rr + it*32;
      union { uint4 v; unsigned short s[8]; } in;
      in.v = *(const uint4*)(zah + (size_t)(r0 + r)*64 + kb*8);
      union { unsigned short s[8]; uint4 v; } o;
      #pragma unroll
      for (int q = 0; q < 8; ++q)
        o.s[q] = f2h(fmaxf(h2f(in.s[q])*sc[q] + sh[q], 0.0f));
      *(uint4*)(S + r*64 + ((kb ^ (r & 7)) * 8)) = o.v;
    }
  }
  __syncthreads();

  const int wrow = (w >> 1) * 64;
  const int wcol = (w & 1) * 64;

  f16x8 af[2][4], bfr[2][4];
  #pragma unroll
  for (int ks = 0; ks < 2; ++ks)
    #pragma unroll
    for (int mi = 0; mi < 4; ++mi) {
      const int row = wrow + mi*16 + mcol;
      af[ks][mi] = *(const f16x8*)(S + row*64 + (((ks*4 + quad) ^ (row & 7)) * 8));
    }
  #pragma unroll
  for (int ks = 0; ks < 2; ++ks)
    #pragma unroll
    for (int ni = 0; ni < 4; ++ni) {
      const int nr = wcol + ni*16 + mcol;
      bfr[ks][ni] = *(const f16x8*)(W2T + nr*64 + ks*32 + quad*8);
    }

  f32x4 acc[4][4];
  #pragma unroll
  for (int mi = 0; mi < 4; ++mi)
    #pragma unroll
    for (int ni = 0; ni < 4; ++ni)
      acc[mi][ni] = (f32x4){0.f, 0.f, 0.f, 0.f};

  #pragma unroll
  for (int ks = 0; ks < 2; ++ks)
    #pragma unroll
    for (int mi = 0; mi < 4; ++mi)
      #pragma unroll
      for (int ni = 0; ni < 4; ++ni)
        acc[mi][ni] = __builtin_amdgcn_mfma_f32_16x16x32_f16(af[ks][mi], bfr[ks][ni], acc[mi][ni], 0, 0, 0);

  __syncthreads();

  float bb[4];
  #pragma unroll
  for (int ni = 0; ni < 4; ++ni) bb[ni] = b2[wcol + ni*16 + mcol];
  float s[4] = {0,0,0,0}, s2[4] = {0,0,0,0};
  #pragma unroll
  for (int mi = 0; mi < 4; ++mi) {
    #pragma unroll
    for (int ni = 0; ni < 4; ++ni) {
      const int col = wcol + ni*16 + mcol;
      const int g = col >> 3, o = col & 7;
      #pragma unroll
      for (int j = 0; j < 4; ++j) {
        const int row = wrow + mi*16 + quad*4 + j;
        const float v = acc[mi][ni][j] + bb[ni];
        S[row*128 + ((g ^ (row & 15)) << 3) + o] = f2h(v);
        s[ni] += v; s2[ni] += v*v;
      }
    }
  }
  #pragma unroll
  for (int ni = 0; ni < 4; ++ni) {
    s[ni]  += __shfl_xor(s[ni], 16);  s[ni]  += __shfl_xor(s[ni], 32);
    s2[ni] += __shfl_xor(s2[ni], 16); s2[ni] += __shfl_xor(s2[ni], 32);
  }
  if (quad == 0) {
    const int rh = w >> 1;
    #pragma unroll
    for (int ni = 0; ni < 4; ++ni) {
      const int col = wcol + ni*16 + mcol;
      ps[rh*256 + col]       = s[ni];
      ps[rh*256 + 128 + col] = s2[ni];
    }
  }
  __syncthreads();

  #pragma unroll
  for (int i = 0; i < 8; ++i) {
    const int u = i*256 + t;
    const int row = u >> 4, gg = u & 15;
    *(uint4*)(zhb + (size_t)(r0 + row)*128 + gg*8) =
        *(const uint4*)(S + row*128 + ((gg ^ (row & 15)) << 3));
  }
  partialB[(size_t)blockIdx.x*256 + t] = ps[t] + ps[256 + t];
}

// ---------------- sum columns of [1024][256] -> [64][256] ----------------
__global__ __launch_bounds__(256) void sumcols256_kernel(const float* __restrict__ partial,
                                                         float* __restrict__ mid) {
  const int b = blockIdx.x, t = threadIdx.x;
  float a = 0.0f;
  #pragma unroll
  for (int i = 0; i < 16; ++i) a += partial[(size_t)(b*16 + i)*256 + t];
  mid[b*256 + t] = a;
}

// ---------------- conv2 layer3 + FULL max fusion: writes per-block col-max partials ----------------
// 2048 blocks: rb = bid & 1023 (128 rows), ch = bid >> 10 (512-col half; same XCD as partner).
// A in LDS; per-chunk B from L2; per-16-row max in regs (quad q holds chunk q), then
// two-phase LDS max over the block's 128 rows -> pmax2[rb][1024] (4 MB). No x2 tensor.
__global__ __launch_bounds__(256, 2) void conv2_l3max_mfma(
    const unsigned short* __restrict__ zhb, const float* __restrict__ ss,
    const unsigned short* __restrict__ W3T,
    float* __restrict__ pmax2) {
  __shared__ unsigned short As[128*128];
  __shared__ float pm[512];
  const int rb = blockIdx.x & 1023, ch = blockIdx.x >> 10;
  const int r0 = rb * 128;
  const int t = threadIdx.x;
  const int lane = t & 63, w = t >> 6;
  const int quad = lane >> 4, mcol = lane & 15;

  // ---- stage A: relu(bn(zhb)) fp16 -> fp16, swizzled ----
  {
    const int kb = t & 15;
    const int rr = t >> 4;
    float sc[8], sh[8];
    #pragma unroll
    for (int q = 0; q < 8; ++q) { sc[q] = ss[kb*8 + q]; sh[q] = ss[128 + kb*8 + q]; }
    #pragma unroll
    for (int it = 0; it < 8; ++it) {
      const int r = rr + it*16;
      union { uint4 v; unsigned short s[8]; } in;
      in.v = *(const uint4*)(zhb + (size_t)(r0 + r)*128 + kb*8);
      union { unsigned short s[8]; uint4 v; } o;
      #pragma unroll
      for (int q = 0; q < 8; ++q)
        o.s[q] = f2h(fmaxf(h2f(in.s[q])*sc[q] + sh[q], 0.0f));
      *(uint4*)(As + r*128 + ((kb ^ (r & 7)) * 8)) = o.v;
    }
  }
  __syncthreads();

  const int wrow = (w >> 1) * 64;
  const int wcol = (w & 1) * 64;

  float res[4][4];   // [mi][ni] ; quad q keeps chunk q's columns

  #pragma unroll 1
  for (int chunk = 0; chunk < 4; ++chunk) {
    const int n0 = ch*512 + chunk*128;

    f32x4 acc[4][4];
    #pragma unroll
    for (int mi = 0; mi < 4; ++mi)
      #pragma unroll
      for (int ni = 0; ni < 4; ++ni)
        acc[mi][ni] = (f32x4){0.f, 0.f, 0.f, 0.f};

    #pragma unroll
    for (int ks = 0; ks < 4; ++ks) {
      f16x8 bfr[4], af[4];
      #pragma unroll
      for (int ni = 0; ni < 4; ++ni) {
        const int nr = n0 + wcol + ni*16 + mcol;
        bfr[ni] = *(const f16x8*)(W3T + (size_t)nr*128 + ks*32 + quad*8);
      }
      #pragma unroll
      for (int mi = 0; mi < 4; ++mi) {
        const int row = wrow + mi*16 + mcol;
        af[mi] = *(const f16x8*)(As + row*128 + (((ks*4 + quad) ^ (row & 7)) * 8));
      }
      #pragma unroll
      for (int mi = 0; mi < 4; ++mi)
        #pragma unroll
        for (int ni = 0; ni < 4; ++ni)
          acc[mi][ni] = __builtin_amdgcn_mfma_f32_16x16x32_f16(af[mi], bfr[ni], acc[mi][ni], 0, 0, 0);
    }

    // max over 16 rows of each tile; quad==chunk lanes keep the value
    #pragma unroll
    for (int mi = 0; mi < 4; ++mi) {
      #pragma unroll
      for (int ni = 0; ni < 4; ++ni) {
        f32x4 a = acc[mi][ni];
        float m = fmaxf(fmaxf(a[0], a[1]), fmaxf(a[2], a[3]));
        m = fmaxf(m, __shfl_xor(m, 16));
        m = fmaxf(m, __shfl_xor(m, 32));
        if (quad == chunk) res[mi][ni] = m;
      }
    }
  }

  // ---- block-level max over 128 rows: two-phase LDS ----
  float m4[4];
  #pragma unroll
  for (int ni = 0; ni < 4; ++ni)
    m4[ni] = fmaxf(fmaxf(res[0][ni], res[1][ni]), fmaxf(res[2][ni], res[3][ni]));

  if (w < 2) {
    #pragma unroll
    for (int ni = 0; ni < 4; ++ni)
      pm[quad*128 + wcol + ni*16 + mcol] = m4[ni];
  }
  __syncthreads();
  if (w >= 2) {
    #pragma unroll
    for (int ni = 0; ni < 4; ++ni) {
      const int pc = quad*128 + wcol + ni*16 + mcol;
      pm[pc] = fmaxf(pm[pc], m4[ni]);
    }
  }
  __syncthreads();

  pmax2[(size_t)rb*1024 + ch*512 + t]       = pm[t];
  pmax2[(size_t)rb*1024 + ch*512 + 256 + t] = pm[256 + t];
}

// ---------------- final pool: max over 128 row-blocks per graph + b3 ----------------
__global__ __launch_bounds__(256) void pool_final_kernel(const float* __restrict__ pmax2,
    const float* __restrict__ b3, float* __restrict__ g) {
  const int b = blockIdx.x >> 2, q = blockIdx.x & 3;
  const int c = q*256 + threadIdx.x;
  const float* p = pmax2 + (size_t)b*128*1024 + c;
  float m = -INFINITY;
  for (int rb = 0; rb < 128; ++rb) m = fmaxf(m, p[(size_t)rb*1024]);
  g[b*1024 + c] = m + b3[c];
}

// ---------------- final linear (partials over c-quarters) ----------------
__global__ __launch_bounds__(256) void lin_kernel(const float* __restrict__ g,
    const float* __restrict__ W, float* __restrict__ zpart) {
  const int b = blockIdx.x >> 2, q = blockIdx.x & 3;
  const int o = threadIdx.x;
  const float* gb = g + b*1024 + q*256;
  const float* Wq = W + q*256*256;
  float acc = 0.0f;
  for (int c = 0; c < 256; ++c) acc += gb[c] * Wq[c*256 + o];
  zpart[blockIdx.x*256 + o] = acc;
}

// ---------------- final BN(8 rows) + relu ----------------
__global__ __launch_bounds__(256) void final_kernel(const float* __restrict__ zpart,
    const float* __restrict__ lb, const float* __restrict__ lg,
    const float* __restrict__ lbe, float* __restrict__ out) {
  const int o = threadIdx.x;
  float z[NB]; float s = 0.0f, s2 = 0.0f;
  #pragma unroll
  for (int b = 0; b < NB; ++b) {
    float v = lb[o];
    #pragma unroll
    for (int q = 0; q < 4; ++q) v += zpart[(b*4+q)*256 + o];
    z[b] = v; s += v; s2 += v*v;
  }
  const float mu  = s * 0.125f;
  const float var = s2 * 0.125f - mu*mu;
  const float inv = rsqrtf(var + 1e-5f);
  const float sc = lg[o]*inv, sh = lbe[o] - mu*sc;
  #pragma unroll
  for (int b = 0; b < NB; ++b) out[b*256 + o] = fmaxf(z[b]*sc + sh, 0.0f);
}

extern "C" void kernel_launch(void* const* d_in, const int* in_sizes, int n_in,
                              void* d_out, int out_size, void* d_ws, size_t ws_size,
                              hipStream_t stream) {
  const float* pos    = (const float*)d_in[0];
  const float* c1_W1  = (const float*)d_in[2];
  const float* c1_b1  = (const float*)d_in[3];
  const float* c1_g1  = (const float*)d_in[4];
  const float* c1_be1 = (const float*)d_in[5];
  const float* c1_W2  = (const float*)d_in[6];
  const float* c1_b2  = (const float*)d_in[7];
  const float* c2_W1  = (const float*)d_in[8];
  const float* c2_b1  = (const float*)d_in[9];
  const float* c2_g1  = (const float*)d_in[10];
  const float* c2_be1 = (const float*)d_in[11];
  const float* c2_W2  = (const float*)d_in[12];
  const float* c2_b2  = (const float*)d_in[13];
  const float* c2_g2  = (const float*)d_in[14];
  const float* c2_be2 = (const float*)d_in[15];
  const float* c2_W3  = (const float*)d_in[16];
  const float* c2_b3  = (const float*)d_in[17];
  const float* lin_W  = (const float*)d_in[18];
  const float* lin_b  = (const float*)d_in[19];
  const float* lin_g  = (const float*)d_in[20];
  const float* lin_be = (const float*)d_in[21];
  float* out = (float*)d_out;

  char* ws = (char*)d_ws;
  int*   idx     = (int*)  (ws + 0);                 // 512 KB
  float* rel     = (float*)(ws + 524288);            // 1.5 MB
  float* ss1     = (float*)(ws + 2097152);           // 128
  float* ssA     = (float*)(ws + 2097152 + 512);     // 128
  float* ssB     = (float*)(ws + 2097152 + 1024);    // 256
  float* zpart   = (float*)(ws + 2097152 + 2048);    // 8192
  float* gpool   = (float*)(ws + 2097152 + 2048 + 32768);          // 8192
  float* mid     = (float*)(ws + 2097152 + 2048 + 65536);          // 64 x 128 (32 KB)
  float* midB    = (float*)(ws + 2097152 + 2048 + 65536 + 32768);  // 64 x 256 (64 KB)
  unsigned short* W2T = (unsigned short*)(ws + 2164736 + 131072);  // 16 KB
  // bufA region (33.5 MB): z1h (fp16) -> zah (fp16) -> pmax2 (4 MB)
  unsigned short* z1h = (unsigned short*)(ws + 2426880);
  unsigned short* zah = (unsigned short*)(ws + 2426880);
  float* pmax2   = (float*)(ws + 2426880);
  float* x1      = (float*)(ws + 35981312);          // 2 MB (x1, then W3T)
  unsigned short* W3T = (unsigned short*)(ws + 35981312);
  unsigned short* zhb = (unsigned short*)(ws + 38078464);  // 33.5 MB region: partials, then fp16 zb
  float* partialP= (float*)(ws + 38078464);                // partials for conv1_l1 / conv2_l1
  float* partialB= (float*)(ws + 71632896);          // 1 MB  (1024 x 256)

  const float invPK = 1.0f / (float)PK;

  knn_kernel<<<PTS/4, 256, 0, stream>>>(pos, idx, rel);
  conv1_l1_kernel<<<PK/64, 256, 0, stream>>>(pos, idx, rel, c1_W1, c1_b1, z1h, partialP);
  sumcols128_kernel<<<64, 256, 0, stream>>>(partialP, 32, mid);
  stats_final_kernel<<<1, 256, 0, stream>>>(mid, 64, 64, invPK, c1_g1, c1_be1, ss1);
  conv1_l2max_kernel<<<PTS/4, 256, 0, stream>>>(z1h, ss1, c1_W2, c1_b2, x1);
  conv2_l1_kernel<<<PTS, 256, 0, stream>>>(x1, idx, rel, c2_W1, c2_b1, zah, partialP);
  w3t_kernel<<<128, 256, 0, stream>>>(c2_W3, W3T);
  w2t_kernel<<<8, 256, 0, stream>>>(c2_W2, W2T);
  sumcols128_kernel<<<64, 256, 0, stream>>>(partialP, 128, mid);
  stats_final_kernel<<<1, 256, 0, stream>>>(mid, 64, 64, invPK, c2_g1, c2_be1, ssA);
  conv2_l2_mfma<<<PK/128, 256, 0, stream>>>(zah, ssA, W2T, c2_b2, zhb, partialB);
  sumcols256_kernel<<<64, 256, 0, stream>>>(partialB, midB);
  stats_final_kernel<<<1, 256, 0, stream>>>(midB, 64, 128, invPK, c2_g2, c2_be2, ssB);
  conv2_l3max_mfma<<<PK/64, 256, 0, stream>>>(zhb, ssB, W3T, pmax2);
  pool_final_kernel<<<NB*4, 256, 0, stream>>>(pmax2, c2_b3, gpool);
  lin_kernel<<<32, 256, 0, stream>>>(gpool, lin_W, zpart);
  final_kernel<<<1, 256, 0, stream>>>(zpart, lin_b, lin_g, lin_be, out);
}

// Round 12
// 399.416 us; speedup vs baseline: 1.0468x; 1.0468x over previous
//
#include <hip/hip_runtime.h>
#include <math.h>

#define NB   8
#define NPTS 1024
#define PTS  8192      // NB*NPTS
#define KNN  16
#define PK   (PTS*KNN) // 131072

typedef __attribute__((ext_vector_type(8))) _Float16 f16x8;
typedef __attribute__((ext_vector_type(4))) float f32x4;

__device__ __forceinline__ unsigned short f2h(float f) {
  _Float16 h = (_Float16)f;
  union { _Float16 h; unsigned short u; } c; c.h = h;
  return c.u;
}
__device__ __forceinline__ float h2f(unsigned short u) {
  union { unsigned short u; _Float16 h; } c; c.u = u;
  return (float)c.h;
}

// ---------------- kNN: one WAVE per point; register-resident top-16, barrier-free ----------------
__global__ __launch_bounds__(256) void knn_kernel(const float* __restrict__ pos,
                                                  int* __restrict__ idx,
                                                  float* __restrict__ rel) {
  __shared__ float px[NPTS], py[NPTS], pz[NPTS];
  const int t = threadIdx.x;
  const int wv = t >> 6, lane = t & 63;
  const int b = blockIdx.x;
  const int graph = b >> 8;             // 256 blocks per graph
  const int base = graph << 10;
  for (int j = t; j < NPTS; j += 256) {
    px[j] = pos[3*(base+j)];
    py[j] = pos[3*(base+j)+1];
    pz[j] = pos[3*(base+j)+2];
  }
  __syncthreads();

  const int il = ((b & 255) << 2) + wv; // point index within graph
  const float pix = px[il], piy = py[il], piz = pz[il];
  const float sqi = pix*pix + piy*piy + piz*piz;

  float d[16];
  #pragma unroll
  for (int q = 0; q < 16; ++q) {
    const int j = (q << 6) + lane;
    const float x = px[j], y = py[j], z = pz[j];
    const float sqj = x*x + y*y + z*z;
    const float dt  = pix*x + piy*y + piz*z;
    d[q] = sqi + sqj - 2.0f*dt;
  }
  float mv = d[0]; int mq = 0;
  #pragma unroll
  for (int q = 1; q < 16; ++q) { if (d[q] < mv) { mv = d[q]; mq = q; } }

  int sel = 0;
  for (int s = 0; s < KNN; ++s) {
    float v = mv; int j = (mq << 6) + lane;
    #pragma unroll
    for (int m = 1; m <= 32; m <<= 1) {
      const float v2 = __shfl_xor(v, m);
      const int   j2 = __shfl_xor(j, m);
      if (v2 < v || (v2 == v && j2 < j)) { v = v2; j = j2; }
    }
    if (lane == s) sel = j;
    if (lane == (j & 63)) {
      const int wq = j >> 6;
      #pragma unroll
      for (int q = 0; q < 16; ++q) if (q == wq) d[q] = INFINITY;
      mv = d[0]; mq = 0;
      #pragma unroll
      for (int q = 1; q < 16; ++q) { if (d[q] < mv) { mv = d[q]; mq = q; } }
    }
  }

  if (lane < KNN) {
    const int i = base + il;
    const int r = i*KNN + lane;
    idx[r] = base + sel;
    rel[3*r]   = px[sel] - pix;
    rel[3*r+1] = py[sel] - piy;
    rel[3*r+2] = pz[sel] - piz;
  }
}

// ---------------- weight prep: W3T [1024][128], W2T [128][64], w1T [64][64] (all fp16) ----------------
__global__ __launch_bounds__(256) void wprep_kernel(const float* __restrict__ W3,
    const float* __restrict__ W2, const float* __restrict__ W1c2,
    unsigned short* __restrict__ W3T, unsigned short* __restrict__ W2T,
    unsigned short* __restrict__ w1T) {
  const int b = blockIdx.x, t = threadIdx.x;
  if (b < 128) {
    for (int n = t; n < 1024; n += 256) W3T[n*128 + b] = f2h(W3[(size_t)b*1024 + n]);
  } else if (b < 132) {
    for (int id = (b-128)*2048 + t; id < (b-127)*2048; id += 256) {
      const int n = id >> 6, k = id & 63;
      W2T[n*64 + k] = f2h(W2[k*128 + n]);
    }
  } else {
    for (int id = (b-132)*1024 + t; id < (b-131)*1024; id += 256) {
      const int n = id >> 6, k = id & 63;
      w1T[n*64 + k] = f2h(W1c2[k*64 + n]);
    }
  }
}

// ---------------- conv1 layer1 + atomic BN partials; z1 stored fp16 ----------------
__global__ __launch_bounds__(256) void conv1_l1_kernel(const float* __restrict__ pos,
    const int* __restrict__ idx, const float* __restrict__ rel,
    const float* __restrict__ W1, const float* __restrict__ b1,
    unsigned short* __restrict__ z1h, float* __restrict__ mid1) {
  const int r0 = blockIdx.x * 64;
  const int t = threadIdx.x;
  __shared__ float f[64][6];
  __shared__ float ls[256], ls2[256];
  if (t < 64) {
    const int r = r0 + t;
    const int j = idx[r];
    f[t][0] = pos[3*j]; f[t][1] = pos[3*j+1]; f[t][2] = pos[3*j+2];
    f[t][3] = rel[3*r]; f[t][4] = rel[3*r+1]; f[t][5] = rel[3*r+2];
  }
  __syncthreads();
  const int c = t & 63, rg = t >> 6;
  float w[6];
  #pragma unroll
  for (int q = 0; q < 6; ++q) w[q] = W1[q*64 + c];
  const float bb = b1[c];
  float s = 0.0f, s2 = 0.0f;
  for (int j = 0; j < 16; ++j) {
    const int lr = rg + 4*j;
    float z = bb;
    #pragma unroll
    for (int q = 0; q < 6; ++q) z += f[lr][q]*w[q];
    z1h[(size_t)(r0+lr)*64 + c] = f2h(z);
    s += z; s2 += z*z;
  }
  ls[t] = s; ls2[t] = s2;
  __syncthreads();
  if (t < 64) {
    float a  = ls[t] + ls[t+64] + ls[t+128] + ls[t+192];
    float a2 = ls2[t] + ls2[t+64] + ls2[t+128] + ls2[t+192];
    atomicAdd(&mid1[t], a);
    atomicAdd(&mid1[64 + t], a2);
  }
}

__global__ __launch_bounds__(256) void stats_final_kernel(const float* __restrict__ partial,
    int G, int C, float invRows,
    const float* __restrict__ gamma, const float* __restrict__ beta,
    float* __restrict__ ss) {
  const int t = threadIdx.x;
  if (t >= C) return;
  float s = 0.0f, s2 = 0.0f;
  for (int g = 0; g < G; ++g) { s += partial[g*2*C + t]; s2 += partial[g*2*C + C + t]; }
  const float mu  = s * invRows;
  const float var = s2 * invRows - mu*mu;
  const float sc  = gamma[t] * rsqrtf(var + 1e-5f);
  ss[t] = sc; ss[C + t] = beta[t] - mu*sc;
}

// ---------------- conv1 layer2 + max: 4 points per block (one wave each), fp16 z1 ----------------
__global__ __launch_bounds__(256) void conv1_l2max_kernel(const unsigned short* __restrict__ z1h,
    const float* __restrict__ ss, const float* __restrict__ W2,
    const float* __restrict__ b2, float* __restrict__ x1) {
  __shared__ float h[4][KNN][64];
  const int wv = threadIdx.x >> 6, t = threadIdx.x & 63;
  const int i = blockIdx.x*4 + wv;
  const float sc = ss[t], sh = ss[64+t];
  #pragma unroll
  for (int k = 0; k < KNN; ++k) {
    const float z = h2f(z1h[(size_t)(i*KNN+k)*64 + t]);
    h[wv][k][t] = fmaxf(z*sc + sh, 0.0f);
  }
  __syncthreads();
  float w[64];
  #pragma unroll
  for (int d = 0; d < 64; ++d) w[d] = W2[d*64 + t];
  const float bb = b2[t];
  float acc = -INFINITY;
  for (int k = 0; k < KNN; ++k) {
    float y = bb;
    #pragma unroll
    for (int d = 0; d < 64; ++d) y += h[wv][k][d]*w[d];
    acc = fmaxf(acc, y);
  }
  x1[(size_t)i*64 + t] = acc;
}

// ---------------- conv2 layer1: fp16 MFMA (gather + rank-3 rel fixup) + atomic BN partials ----------------
// 1024 blocks x 128 rows; N=64, K=64 MFMA on x1[idx[r]] + VALU fixup for 3 rel channels.
__global__ __launch_bounds__(256) void conv2_l1_mfma(
    const float* __restrict__ x1, const int* __restrict__ idx,
    const float* __restrict__ rel, const unsigned short* __restrict__ w1T,
    const float* __restrict__ W1full, const float* __restrict__ b1,
    unsigned short* __restrict__ zah, float* __restrict__ midA) {
  __shared__ unsigned short S[128*64];
  __shared__ int   idxr[128];
  __shared__ float rl[128*3];
  __shared__ float ps[256];
  const int r0 = blockIdx.x * 128;
  const int t = threadIdx.x;
  const int lane = t & 63, w = t >> 6;
  const int quad = lane >> 4, mcol = lane & 15;

  // phase 0: idx + rel rows to LDS
  if (t < 128) idxr[t] = idx[r0 + t];
  else if (t < 224) *(float4*)(rl + (t-128)*4) = *(const float4*)(rel + (size_t)r0*3 + (t-128)*4);
  __syncthreads();

  // phase 1: gather x1 rows -> fp16, swizzled
  {
    const int kb = t & 7;           // 16B block along K (8 ch)
    const int rr = t >> 3;          // 32 rows per pass
    #pragma unroll
    for (int it = 0; it < 4; ++it) {
      const int r = rr + it*32;
      const int gj = idxr[r];
      const float* src = x1 + (size_t)gj*64 + kb*8;
      const float4 v0 = *(const float4*)(src);
      const float4 v1 = *(const float4*)(src + 4);
      union { unsigned short s[8]; uint4 v; } o;
      o.s[0] = f2h(v0.x); o.s[1] = f2h(v0.y); o.s[2] = f2h(v0.z); o.s[3] = f2h(v0.w);
      o.s[4] = f2h(v1.x); o.s[5] = f2h(v1.y); o.s[6] = f2h(v1.z); o.s[7] = f2h(v1.w);
      *(uint4*)(S + r*64 + ((kb ^ (r & 7)) * 8)) = o.v;
    }
  }
  __syncthreads();

  const int wrow = (w >> 1) * 64;
  const int wcol = (w & 1) * 32;

  f16x8 af[2][4], bfr[2][2];
  #pragma unroll
  for (int ks = 0; ks < 2; ++ks)
    #pragma unroll
    for (int mi = 0; mi < 4; ++mi) {
      const int row = wrow + mi*16 + mcol;
      af[ks][mi] = *(const f16x8*)(S + row*64 + (((ks*4 + quad) ^ (row & 7)) * 8));
    }
  #pragma unroll
  for (int ks = 0; ks < 2; ++ks)
    #pragma unroll
    for (int ni = 0; ni < 2; ++ni) {
      const int nr = wcol + ni*16 + mcol;
      bfr[ks][ni] = *(const f16x8*)(w1T + nr*64 + ks*32 + quad*8);
    }

  f32x4 acc[4][2];
  #pragma unroll
  for (int mi = 0; mi < 4; ++mi)
    #pragma unroll
    for (int ni = 0; ni < 2; ++ni)
      acc[mi][ni] = (f32x4){0.f, 0.f, 0.f, 0.f};

  #pragma unroll
  for (int ks = 0; ks < 2; ++ks)
    #pragma unroll
    for (int mi = 0; mi < 4; ++mi)
      #pragma unroll
      for (int ni = 0; ni < 2; ++ni)
        acc[mi][ni] = __builtin_amdgcn_mfma_f32_16x16x32_f16(af[ks][mi], bfr[ks][ni], acc[mi][ni], 0, 0, 0);

  __syncthreads();   // done reading S; reuse as out tile

  // epilogue: + b1 + rel rank-3, fp16 repack, sums
  float bb[2], wr0[2], wr1[2], wr2[2];
  #pragma unroll
  for (int ni = 0; ni < 2; ++ni) {
    const int col = wcol + ni*16 + mcol;
    bb[ni]  = b1[col];
    wr0[ni] = W1full[64*64 + col];
    wr1[ni] = W1full[65*64 + col];
    wr2[ni] = W1full[66*64 + col];
  }
  float s[2] = {0,0}, s2[2] = {0,0};
  #pragma unroll
  for (int mi = 0; mi < 4; ++mi) {
    #pragma unroll
    for (int j = 0; j < 4; ++j) {
      const int row = wrow + mi*16 + quad*4 + j;
      const float r0v = rl[row*3], r1v = rl[row*3+1], r2v = rl[row*3+2];
      #pragma unroll
      for (int ni = 0; ni < 2; ++ni) {
        const int col = wcol + ni*16 + mcol;
        const int g = col >> 3, o = col & 7;
        const float v = acc[mi][ni][j] + bb[ni] + r0v*wr0[ni] + r1v*wr1[ni] + r2v*wr2[ni];
        S[row*64 + ((g ^ (row & 7)) << 3) + o] = f2h(v);
        s[ni] += v; s2[ni] += v*v;
      }
    }
  }
  #pragma unroll
  for (int ni = 0; ni < 2; ++ni) {
    s[ni]  += __shfl_xor(s[ni], 16);  s[ni]  += __shfl_xor(s[ni], 32);
    s2[ni] += __shfl_xor(s2[ni], 16); s2[ni] += __shfl_xor(s2[ni], 32);
  }
  if (quad == 0) {
    const int rh = w >> 1;
    #pragma unroll
    for (int ni = 0; ni < 2; ++ni) {
      const int col = wcol + ni*16 + mcol;
      ps[rh*128 + col]      = s[ni];
      ps[rh*128 + 64 + col] = s2[ni];
    }
  }
  __syncthreads();

  // coalesced fp16 flush: 1024 uint4
  #pragma unroll
  for (int i = 0; i < 4; ++i) {
    const int u = i*256 + t;
    const int row = u >> 3, gg = u & 7;
    *(uint4*)(zah + (size_t)(r0 + row)*64 + gg*8) =
        *(const uint4*)(S + row*64 + ((gg ^ (row & 7)) << 3));
  }
  if (t < 128) atomicAdd(&midA[t], ps[t] + ps[128 + t]);
}

// ---------------- conv2 layer2: fp16 MFMA + atomic BN-stats; reads fp16 za, writes fp16 zb ----------------
__global__ __launch_bounds__(256) void conv2_l2_mfma(
    const unsigned short* __restrict__ zah, const float* __restrict__ ss,
    const unsigned short* __restrict__ W2T, const float* __restrict__ b2,
    unsigned short* __restrict__ zhb, float* __restrict__ midB) {
  __shared__ unsigned short S[128*128];   // first 16KB: As; later: fp16 out tile
  __shared__ float ps[512];
  const int r0 = blockIdx.x * 128;
  const int t = threadIdx.x;
  const int lane = t & 63, w = t >> 6;
  const int quad = lane >> 4, mcol = lane & 15;

  // stage A: 128 rows x 64 ch, relu(bn) -> fp16, swizzled
  {
    const int kb = t & 7;
    const int rr = t >> 3;
    float sc[8], sh[8];
    #pragma unroll
    for (int q = 0; q < 8; ++q) { sc[q] = ss[kb*8 + q]; sh[q] = ss[64 + kb*8 + q]; }
    #pragma unroll
    for (int it = 0; it < 4; ++it) {
      const int r = rr + it*32;
      union { uint4 v; unsigned short s[8]; } in;
      in.v = *(const uint4*)(zah + (size_t)(r0 + r)*64 + kb*8);
      union { unsigned short s[8]; uint4 v; } o;
      #pragma unroll
      for (int q = 0; q < 8; ++q)
        o.s[q] = f2h(fmaxf(h2f(in.s[q])*sc[q] + sh[q], 0.0f));
      *(uint4*)(S + r*64 + ((kb ^ (r & 7)) * 8)) = o.v;
    }
  }
  __syncthreads();

  const int wrow = (w >> 1) * 64;
  const int wcol = (w & 1) * 64;

  f16x8 af[2][4], bfr[2][4];
  #pragma unroll
  for (int ks = 0; ks < 2; ++ks)
    #pragma unroll
    for (int mi = 0; mi < 4; ++mi) {
      const int row = wrow + mi*16 + mcol;
      af[ks][mi] = *(const f16x8*)(S + row*64 + (((ks*4 + quad) ^ (row & 7)) * 8));
    }
  #pragma unroll
  for (int ks = 0; ks < 2; ++ks)
    #pragma unroll
    for (int ni = 0; ni < 4; ++ni) {
      const int nr = wcol + ni*16 + mcol;
      bfr[ks][ni] = *(const f16x8*)(W2T + nr*64 + ks*32 + quad*8);
    }

  f32x4 acc[4][4];
  #pragma unroll
  for (int mi = 0; mi < 4; ++mi)
    #pragma unroll
    for (int ni = 0; ni < 4; ++ni)
      acc[mi][ni] = (f32x4){0.f, 0.f, 0.f, 0.f};

  #pragma unroll
  for (int ks = 0; ks < 2; ++ks)
    #pragma unroll
    for (int mi = 0; mi < 4; ++mi)
      #pragma unroll
      for (int ni = 0; ni < 4; ++ni)
        acc[mi][ni] = __builtin_amdgcn_mfma_f32_16x16x32_f16(af[ks][mi], bfr[ks][ni], acc[mi][ni], 0, 0, 0);

  __syncthreads();

  float bb[4];
  #pragma unroll
  for (int ni = 0; ni < 4; ++ni) bb[ni] = b2[wcol + ni*16 + mcol];
  float s[4] = {0,0,0,0}, s2[4] = {0,0,0,0};
  #pragma unroll
  for (int mi = 0; mi < 4; ++mi) {
    #pragma unroll
    for (int ni = 0; ni < 4; ++ni) {
      const int col = wcol + ni*16 + mcol;
      const int g = col >> 3, o = col & 7;
      #pragma unroll
      for (int j = 0; j < 4; ++j) {
        const int row = wrow + mi*16 + quad*4 + j;
        const float v = acc[mi][ni][j] + bb[ni];
        S[row*128 + ((g ^ (row & 15)) << 3) + o] = f2h(v);
        s[ni] += v; s2[ni] += v*v;
      }
    }
  }
  #pragma unroll
  for (int ni = 0; ni < 4; ++ni) {
    s[ni]  += __shfl_xor(s[ni], 16);  s[ni]  += __shfl_xor(s[ni], 32);
    s2[ni] += __shfl_xor(s2[ni], 16); s2[ni] += __shfl_xor(s2[ni], 32);
  }
  if (quad == 0) {
    const int rh = w >> 1;
    #pragma unroll
    for (int ni = 0; ni < 4; ++ni) {
      const int col = wcol + ni*16 + mcol;
      ps[rh*256 + col]       = s[ni];
      ps[rh*256 + 128 + col] = s2[ni];
    }
  }
  __syncthreads();

  #pragma unroll
  for (int i = 0; i < 8; ++i) {
    const int u = i*256 + t;
    const int row = u >> 4, gg = u & 15;
    *(uint4*)(zhb + (size_t)(r0 + row)*128 + gg*8) =
        *(const uint4*)(S + row*128 + ((gg ^ (row & 15)) << 3));
  }
  atomicAdd(&midB[t], ps[t] + ps[256 + t]);
}

// ---------------- conv2 layer3 + FULL max fusion: writes per-block col-max partials ----------------
__global__ __launch_bounds__(256, 2) void conv2_l3max_mfma(
    const unsigned short* __restrict__ zhb, const float* __restrict__ ss,
    const unsigned short* __restrict__ W3T,
    float* __restrict__ pmax2) {
  __shared__ unsigned short As[128*128];
  __shared__ float pm[512];
  const int rb = blockIdx.x & 1023, ch = blockIdx.x >> 10;
  const int r0 = rb * 128;
  const int t = threadIdx.x;
  const int lane = t & 63, w = t >> 6;
  const int quad = lane >> 4, mcol = lane & 15;

  // ---- stage A: relu(bn(zhb)) fp16 -> fp16, swizzled ----
  {
    const int kb = t & 15;
    const int rr = t >> 4;
    float sc[8], sh[8];
    #pragma unroll
    for (int q = 0; q < 8; ++q) { sc[q] = ss[kb*8 + q]; sh[q] = ss[128 + kb*8 + q]; }
    #pragma unroll
    for (int it = 0; it < 8; ++it) {
      const int r = rr + it*16;
      union { uint4 v; unsigned short s[8]; } in;
      in.v = *(const uint4*)(zhb + (size_t)(r0 + r)*128 + kb*8);
      union { unsigned short s[8]; uint4 v; } o;
      #pragma unroll
      for (int q = 0; q < 8; ++q)
        o.s[q] = f2h(fmaxf(h2f(in.s[q])*sc[q] + sh[q], 0.0f));
      *(uint4*)(As + r*128 + ((kb ^ (r & 7)) * 8)) = o.v;
    }
  }
  __syncthreads();

  const int wrow = (w >> 1) * 64;
  const int wcol = (w & 1) * 64;

  float res[4][4];   // [mi][ni] ; quad q keeps chunk q's columns

  #pragma unroll 1
  for (int chunk = 0; chunk < 4; ++chunk) {
    const int n0 = ch*512 + chunk*128;

    f32x4 acc[4][4];
    #pragma unroll
    for (int mi = 0; mi < 4; ++mi)
      #pragma unroll
      for (int ni = 0; ni < 4; ++ni)
        acc[mi][ni] = (f32x4){0.f, 0.f, 0.f, 0.f};

    #pragma unroll
    for (int ks = 0; ks < 4; ++ks) {
      f16x8 bfr[4], af[4];
      #pragma unroll
      for (int ni = 0; ni < 4; ++ni) {
        const int nr = n0 + wcol + ni*16 + mcol;
        bfr[ni] = *(const f16x8*)(W3T + (size_t)nr*128 + ks*32 + quad*8);
      }
      #pragma unroll
      for (int mi = 0; mi < 4; ++mi) {
        const int row = wrow + mi*16 + mcol;
        af[mi] = *(const f16x8*)(As + row*128 + (((ks*4 + quad) ^ (row & 7)) * 8));
      }
      #pragma unroll
      for (int mi = 0; mi < 4; ++mi)
        #pragma unroll
        for (int ni = 0; ni < 4; ++ni)
          acc[mi][ni] = __builtin_amdgcn_mfma_f32_16x16x32_f16(af[mi], bfr[ni], acc[mi][ni], 0, 0, 0);
    }

    #pragma unroll
    for (int mi = 0; mi < 4; ++mi) {
      #pragma unroll
      for (int ni = 0; ni < 4; ++ni) {
        f32x4 a = acc[mi][ni];
        float m = fmaxf(fmaxf(a[0], a[1]), fmaxf(a[2], a[3]));
        m = fmaxf(m, __shfl_xor(m, 16));
        m = fmaxf(m, __shfl_xor(m, 32));
        if (quad == chunk) res[mi][ni] = m;
      }
    }
  }

  // ---- block-level max over 128 rows: two-phase LDS ----
  float m4[4];
  #pragma unroll
  for (int ni = 0; ni < 4; ++ni)
    m4[ni] = fmaxf(fmaxf(res[0][ni], res[1][ni]), fmaxf(res[2][ni], res[3][ni]));

  if (w < 2) {
    #pragma unroll
    for (int ni = 0; ni < 4; ++ni)
      pm[quad*128 + wcol + ni*16 + mcol] = m4[ni];
  }
  __syncthreads();
  if (w >= 2) {
    #pragma unroll
    for (int ni = 0; ni < 4; ++ni) {
      const int pc = quad*128 + wcol + ni*16 + mcol;
      pm[pc] = fmaxf(pm[pc], m4[ni]);
    }
  }
  __syncthreads();

  pmax2[(size_t)rb*1024 + ch*512 + t]       = pm[t];
  pmax2[(size_t)rb*1024 + ch*512 + 256 + t] = pm[256 + t];
}

// ---------------- final pool: max over 128 row-blocks per graph + b3 ----------------
__global__ __launch_bounds__(256) void pool_final_kernel(const float* __restrict__ pmax2,
    const float* __restrict__ b3, float* __restrict__ g) {
  const int b = blockIdx.x >> 2, q = blockIdx.x & 3;
  const int c = q*256 + threadIdx.x;
  const float* p = pmax2 + (size_t)b*128*1024 + c;
  float m = -INFINITY;
  for (int rb = 0; rb < 128; ++rb) m = fmaxf(m, p[(size_t)rb*1024]);
  g[b*1024 + c] = m + b3[c];
}

// ---------------- final linear (partials over c-quarters) ----------------
__global__ __launch_bounds__(256) void lin_kernel(const float* __restrict__ g,
    const float* __restrict__ W, float* __restrict__ zpart) {
  const int b = blockIdx.x >> 2, q = blockIdx.x & 3;
  const int o = threadIdx.x;
  const float* gb = g + b*1024 + q*256;
  const float* Wq = W + q*256*256;
  float acc = 0.0f;
  for (int c = 0; c < 256; ++c) acc += gb[c] * Wq[c*256 + o];
  zpart[blockIdx.x*256 + o] = acc;
}

// ---------------- final BN(8 rows) + relu ----------------
__global__ __launch_bounds__(256) void final_kernel(const float* __restrict__ zpart,
    const float* __restrict__ lb, const float* __restrict__ lg,
    const float* __restrict__ lbe, float* __restrict__ out) {
  const int o = threadIdx.x;
  float z[NB]; float s = 0.0f, s2 = 0.0f;
  #pragma unroll
  for (int b = 0; b < NB; ++b) {
    float v = lb[o];
    #pragma unroll
    for (int q = 0; q < 4; ++q) v += zpart[(b*4+q)*256 + o];
    z[b] = v; s += v; s2 += v*v;
  }
  const float mu  = s * 0.125f;
  const float var = s2 * 0.125f - mu*mu;
  const float inv = rsqrtf(var + 1e-5f);
  const float sc = lg[o]*inv, sh = lbe[o] - mu*sc;
  #pragma unroll
  for (int b = 0; b < NB; ++b) out[b*256 + o] = fmaxf(z[b]*sc + sh, 0.0f);
}

extern "C" void kernel_launch(void* const* d_in, const int* in_sizes, int n_in,
                              void* d_out, int out_size, void* d_ws, size_t ws_size,
                              hipStream_t stream) {
  const float* pos    = (const float*)d_in[0];
  const float* c1_W1  = (const float*)d_in[2];
  const float* c1_b1  = (const float*)d_in[3];
  const float* c1_g1  = (const float*)d_in[4];
  const float* c1_be1 = (const float*)d_in[5];
  const float* c1_W2  = (const float*)d_in[6];
  const float* c1_b2  = (const float*)d_in[7];
  const float* c2_W1  = (const float*)d_in[8];
  const float* c2_b1  = (const float*)d_in[9];
  const float* c2_g1  = (const float*)d_in[10];
  const float* c2_be1 = (const float*)d_in[11];
  const float* c2_W2  = (const float*)d_in[12];
  const float* c2_b2  = (const float*)d_in[13];
  const float* c2_g2  = (const float*)d_in[14];
  const float* c2_be2 = (const float*)d_in[15];
  const float* c2_W3  = (const float*)d_in[16];
  const float* c2_b3  = (const float*)d_in[17];
  const float* lin_W  = (const float*)d_in[18];
  const float* lin_b  = (const float*)d_in[19];
  const float* lin_g  = (const float*)d_in[20];
  const float* lin_be = (const float*)d_in[21];
  float* out = (float*)d_out;

  char* ws = (char*)d_ws;
  int*   idx     = (int*)  (ws + 0);                 // 512 KB
  float* rel     = (float*)(ws + 524288);            // 1.5 MB
  float* ss1     = (float*)(ws + 2097152);           // 128
  float* ssA     = (float*)(ws + 2097152 + 512);     // 128
  float* ssB     = (float*)(ws + 2097152 + 1024);    // 256
  float* zpart   = (float*)(ws + 2097152 + 2048);    // 8192
  float* gpool   = (float*)(ws + 2097152 + 2048 + 32768);          // 8192
  float* mid1    = (float*)(ws + 2164736);           // 128   } zeroed
  float* midA    = (float*)(ws + 2164736 + 512);     // 128   } by one
  float* midB    = (float*)(ws + 2164736 + 1024);    // 256   } memset
  unsigned short* W2T = (unsigned short*)(ws + 2295808);  // 16 KB
  unsigned short* w1T = (unsigned short*)(ws + 2312192);  // 8 KB
  // bufA region (33.5 MB): z1h (fp16) -> zah (fp16) -> pmax2 (4 MB)
  unsigned short* z1h = (unsigned short*)(ws + 2426880);
  unsigned short* zah = (unsigned short*)(ws + 2426880);
  float* pmax2   = (float*)(ws + 2426880);
  float* x1      = (float*)(ws + 35981312);          // 2 MB
  unsigned short* zhb = (unsigned short*)(ws + 38078464);  // 33.5 MB fp16 zb
  unsigned short* W3T = (unsigned short*)(ws + 71632896);  // 256 KB

  const float invPK = 1.0f / (float)PK;

  hipMemsetAsync(ws + 2164736, 0, 2048, stream);   // zero mid1/midA/midB
  wprep_kernel<<<136, 256, 0, stream>>>(c2_W3, c2_W2, c2_W1, W3T, W2T, w1T);
  knn_kernel<<<PTS/4, 256, 0, stream>>>(pos, idx, rel);
  conv1_l1_kernel<<<PK/64, 256, 0, stream>>>(pos, idx, rel, c1_W1, c1_b1, z1h, mid1);
  stats_final_kernel<<<1, 256, 0, stream>>>(mid1, 1, 64, invPK, c1_g1, c1_be1, ss1);
  conv1_l2max_kernel<<<PTS/4, 256, 0, stream>>>(z1h, ss1, c1_W2, c1_b2, x1);
  conv2_l1_mfma<<<PK/128, 256, 0, stream>>>(x1, idx, rel, w1T, c2_W1, c2_b1, zah, midA);
  stats_final_kernel<<<1, 256, 0, stream>>>(midA, 1, 64, invPK, c2_g1, c2_be1, ssA);
  conv2_l2_mfma<<<PK/128, 256, 0, stream>>>(zah, ssA, W2T, c2_b2, zhb, midB);
  stats_final_kernel<<<1, 256, 0, stream>>>(midB, 1, 128, invPK, c2_g2, c2_be2, ssB);
  conv2_l3max_mfma<<<PK/64, 256, 0, stream>>>(zhb, ssB, W3T, pmax2);
  pool_final_kernel<<<NB*4, 256, 0, stream>>>(pmax2, c2_b3, gpool);
  lin_kernel<<<32, 256, 0, stream>>>(gpool, lin_W, zpart);
  final_kernel<<<1, 256, 0, stream>>>(zpart, lin_b, lin_g, lin_be, out);
}

// Round 13
// 368.124 us; speedup vs baseline: 1.1358x; 1.0850x over previous
//
#include <hip/hip_runtime.h>
#include <math.h>

#define NB   8
#define NPTS 1024
#define PTS  8192      // NB*NPTS
#define KNN  16
#define PK   (PTS*KNN) // 131072

typedef __attribute__((ext_vector_type(8))) _Float16 f16x8;
typedef __attribute__((ext_vector_type(4))) float f32x4;

__device__ __forceinline__ unsigned short f2h(float f) {
  _Float16 h = (_Float16)f;
  union { _Float16 h; unsigned short u; } c; c.h = h;
  return c.u;
}
__device__ __forceinline__ float h2f(unsigned short u) {
  union { unsigned short u; _Float16 h; } c; c.u = u;
  return (float)c.h;
}

// ---------------- kNN: one WAVE per point; register-resident top-16, barrier-free ----------------
__global__ __launch_bounds__(256) void knn_kernel(const float* __restrict__ pos,
                                                  int* __restrict__ idx,
                                                  float* __restrict__ rel) {
  __shared__ float px[NPTS], py[NPTS], pz[NPTS];
  const int t = threadIdx.x;
  const int wv = t >> 6, lane = t & 63;
  const int b = blockIdx.x;
  const int graph = b >> 8;             // 256 blocks per graph
  const int base = graph << 10;
  for (int j = t; j < NPTS; j += 256) {
    px[j] = pos[3*(base+j)];
    py[j] = pos[3*(base+j)+1];
    pz[j] = pos[3*(base+j)+2];
  }
  __syncthreads();

  const int il = ((b & 255) << 2) + wv; // point index within graph
  const float pix = px[il], piy = py[il], piz = pz[il];
  const float sqi = pix*pix + piy*piy + piz*piz;

  float d[16];
  #pragma unroll
  for (int q = 0; q < 16; ++q) {
    const int j = (q << 6) + lane;
    const float x = px[j], y = py[j], z = pz[j];
    const float sqj = x*x + y*y + z*z;
    const float dt  = pix*x + piy*y + piz*z;
    d[q] = sqi + sqj - 2.0f*dt;
  }
  float mv = d[0]; int mq = 0;
  #pragma unroll
  for (int q = 1; q < 16; ++q) { if (d[q] < mv) { mv = d[q]; mq = q; } }

  int sel = 0;
  for (int s = 0; s < KNN; ++s) {
    float v = mv; int j = (mq << 6) + lane;
    #pragma unroll
    for (int m = 1; m <= 32; m <<= 1) {
      const float v2 = __shfl_xor(v, m);
      const int   j2 = __shfl_xor(j, m);
      if (v2 < v || (v2 == v && j2 < j)) { v = v2; j = j2; }
    }
    if (lane == s) sel = j;
    if (lane == (j & 63)) {
      const int wq = j >> 6;
      #pragma unroll
      for (int q = 0; q < 16; ++q) if (q == wq) d[q] = INFINITY;
      mv = d[0]; mq = 0;
      #pragma unroll
      for (int q = 1; q < 16; ++q) { if (d[q] < mv) { mv = d[q]; mq = q; } }
    }
  }

  if (lane < KNN) {
    const int i = base + il;
    const int r = i*KNN + lane;
    idx[r] = base + sel;
    rel[3*r]   = px[sel] - pix;
    rel[3*r+1] = py[sel] - piy;
    rel[3*r+2] = pz[sel] - piz;
  }
}

// ---------------- weight prep: W3T [1024][128], W2T [128][64], w1T [64][64], W2c1T [64][64] ----------------
__global__ __launch_bounds__(256) void wprep_kernel(const float* __restrict__ W3,
    const float* __restrict__ W2, const float* __restrict__ W1c2,
    const float* __restrict__ W2c1,
    unsigned short* __restrict__ W3T, unsigned short* __restrict__ W2T,
    unsigned short* __restrict__ w1T, unsigned short* __restrict__ W2c1T) {
  const int b = blockIdx.x, t = threadIdx.x;
  if (b < 128) {
    for (int n = t; n < 1024; n += 256) W3T[n*128 + b] = f2h(W3[(size_t)b*1024 + n]);
  } else if (b < 132) {
    for (int id = (b-128)*2048 + t; id < (b-127)*2048; id += 256) {
      const int n = id >> 6, k = id & 63;
      W2T[n*64 + k] = f2h(W2[k*128 + n]);
    }
  } else if (b < 136) {
    for (int id = (b-132)*1024 + t; id < (b-131)*1024; id += 256) {
      const int n = id >> 6, k = id & 63;
      w1T[n*64 + k] = f2h(W1c2[k*64 + n]);
    }
  } else {
    for (int id = (b-136)*1024 + t; id < (b-135)*1024; id += 256) {
      const int n = id >> 6, k = id & 63;
      W2c1T[n*64 + k] = f2h(W2c1[k*64 + n]);
    }
  }
}

// ---------------- conv1 layer1 + atomic BN partials; z1 stored fp16 ----------------
__global__ __launch_bounds__(256) void conv1_l1_kernel(const float* __restrict__ pos,
    const int* __restrict__ idx, const float* __restrict__ rel,
    const float* __restrict__ W1, const float* __restrict__ b1,
    unsigned short* __restrict__ z1h, float* __restrict__ mid1) {
  const int r0 = blockIdx.x * 64;
  const int t = threadIdx.x;
  __shared__ float f[64][6];
  __shared__ float ls[256], ls2[256];
  if (t < 64) {
    const int r = r0 + t;
    const int j = idx[r];
    f[t][0] = pos[3*j]; f[t][1] = pos[3*j+1]; f[t][2] = pos[3*j+2];
    f[t][3] = rel[3*r]; f[t][4] = rel[3*r+1]; f[t][5] = rel[3*r+2];
  }
  __syncthreads();
  const int c = t & 63, rg = t >> 6;
  float w[6];
  #pragma unroll
  for (int q = 0; q < 6; ++q) w[q] = W1[q*64 + c];
  const float bb = b1[c];
  float s = 0.0f, s2 = 0.0f;
  for (int j = 0; j < 16; ++j) {
    const int lr = rg + 4*j;
    float z = bb;
    #pragma unroll
    for (int q = 0; q < 6; ++q) z += f[lr][q]*w[q];
    z1h[(size_t)(r0+lr)*64 + c] = f2h(z);
    s += z; s2 += z*z;
  }
  ls[t] = s; ls2[t] = s2;
  __syncthreads();
  if (t < 64) {
    float a  = ls[t] + ls[t+64] + ls[t+128] + ls[t+192];
    float a2 = ls2[t] + ls2[t+64] + ls2[t+128] + ls2[t+192];
    atomicAdd(&mid1[t], a);
    atomicAdd(&mid1[64 + t], a2);
  }
}

__global__ __launch_bounds__(256) void stats_final_kernel(const float* __restrict__ partial,
    int G, int C, float invRows,
    const float* __restrict__ gamma, const float* __restrict__ beta,
    float* __restrict__ ss) {
  const int t = threadIdx.x;
  if (t >= C) return;
  float s = 0.0f, s2 = 0.0f;
  for (int g = 0; g < G; ++g) { s += partial[g*2*C + t]; s2 += partial[g*2*C + C + t]; }
  const float mu  = s * invRows;
  const float var = s2 * invRows - mu*mu;
  const float sc  = gamma[t] * rsqrtf(var + 1e-5f);
  ss[t] = sc; ss[C + t] = beta[t] - mu*sc;
}

// ---------------- conv1 layer2 + max: fp16 MFMA, fused per-point max; x1 out fp16 ----------------
// 1024 blocks x 128 rows (8 points); N=64, K=64. Wave tile 64x32 (acc[4][2]).
__global__ __launch_bounds__(256) void conv1_l2max_mfma(
    const unsigned short* __restrict__ z1h, const float* __restrict__ ss,
    const unsigned short* __restrict__ W2T, const float* __restrict__ b2,
    unsigned short* __restrict__ x1h) {
  __shared__ unsigned short As[128*64];
  const int r0 = blockIdx.x * 128;
  const int t = threadIdx.x;
  const int lane = t & 63, w = t >> 6;
  const int quad = lane >> 4, mcol = lane & 15;

  // stage A: relu(bn(z1h)) -> fp16, swizzled
  {
    const int kb = t & 7, rr = t >> 3;
    float sc[8], sh[8];
    #pragma unroll
    for (int q = 0; q < 8; ++q) { sc[q] = ss[kb*8 + q]; sh[q] = ss[64 + kb*8 + q]; }
    #pragma unroll
    for (int it = 0; it < 4; ++it) {
      const int r = rr + it*32;
      union { uint4 v; unsigned short s[8]; } in;
      in.v = *(const uint4*)(z1h + (size_t)(r0 + r)*64 + kb*8);
      union { unsigned short s[8]; uint4 v; } o;
      #pragma unroll
      for (int q = 0; q < 8; ++q)
        o.s[q] = f2h(fmaxf(h2f(in.s[q])*sc[q] + sh[q], 0.0f));
      *(uint4*)(As + r*64 + ((kb ^ (r & 7)) * 8)) = o.v;
    }
  }
  __syncthreads();

  const int wrow = (w >> 1) * 64;
  const int wncol = (w & 1) * 32;

  f32x4 acc[4][2];
  #pragma unroll
  for (int mi = 0; mi < 4; ++mi)
    #pragma unroll
    for (int ni = 0; ni < 2; ++ni)
      acc[mi][ni] = (f32x4){0.f, 0.f, 0.f, 0.f};

  #pragma unroll
  for (int ks = 0; ks < 2; ++ks) {
    f16x8 af[4], bfr[2];
    #pragma unroll
    for (int mi = 0; mi < 4; ++mi) {
      const int row = wrow + mi*16 + mcol;
      af[mi] = *(const f16x8*)(As + row*64 + (((ks*4 + quad) ^ (row & 7)) * 8));
    }
    #pragma unroll
    for (int ni = 0; ni < 2; ++ni) {
      const int nr = wncol + ni*16 + mcol;
      bfr[ni] = *(const f16x8*)(W2T + nr*64 + ks*32 + quad*8);
    }
    #pragma unroll
    for (int mi = 0; mi < 4; ++mi)
      #pragma unroll
      for (int ni = 0; ni < 2; ++ni)
        acc[mi][ni] = __builtin_amdgcn_mfma_f32_16x16x32_f16(af[mi], bfr[ni], acc[mi][ni], 0, 0, 0);
  }

  float bb[2];
  #pragma unroll
  for (int ni = 0; ni < 2; ++ni) bb[ni] = b2[wncol + ni*16 + mcol];
  #pragma unroll
  for (int mi = 0; mi < 4; ++mi) {
    const int p = blockIdx.x*8 + (w >> 1)*4 + mi;   // 16-row tile = one point
    #pragma unroll
    for (int ni = 0; ni < 2; ++ni) {
      f32x4 a = acc[mi][ni];
      float m = fmaxf(fmaxf(a[0], a[1]), fmaxf(a[2], a[3]));
      m = fmaxf(m, __shfl_xor(m, 16));
      m = fmaxf(m, __shfl_xor(m, 32));
      if (quad == 0) x1h[(size_t)p*64 + wncol + ni*16 + mcol] = f2h(m + bb[ni]);
    }
  }
}

// ---------------- conv2 layer1: fp16 MFMA (fp16 gather + rank-3 rel fixup) + atomic BN partials ----------------
__global__ __launch_bounds__(256) void conv2_l1_mfma(
    const unsigned short* __restrict__ x1h, const int* __restrict__ idx,
    const float* __restrict__ rel, const unsigned short* __restrict__ w1T,
    const float* __restrict__ W1full, const float* __restrict__ b1,
    unsigned short* __restrict__ zah, float* __restrict__ midA) {
  __shared__ unsigned short S[128*64];
  __shared__ int   idxr[128];
  __shared__ float rl[128*3];
  __shared__ float ps[256];
  const int r0 = blockIdx.x * 128;
  const int t = threadIdx.x;
  const int lane = t & 63, w = t >> 6;
  const int quad = lane >> 4, mcol = lane & 15;

  // phase 0: idx + rel rows to LDS
  if (t < 128) idxr[t] = idx[r0 + t];
  else if (t < 224) *(float4*)(rl + (t-128)*4) = *(const float4*)(rel + (size_t)r0*3 + (t-128)*4);
  __syncthreads();

  // phase 1: gather fp16 x1 rows -> LDS, swizzled (no conversion)
  {
    const int kb = t & 7, rr = t >> 3;
    #pragma unroll
    for (int it = 0; it < 4; ++it) {
      const int r = rr + it*32;
      const int gj = idxr[r];
      const uint4 v = *(const uint4*)(x1h + (size_t)gj*64 + kb*8);
      *(uint4*)(S + r*64 + ((kb ^ (r & 7)) * 8)) = v;
    }
  }
  __syncthreads();

  const int wrow = (w >> 1) * 64;
  const int wcol = (w & 1) * 32;

  f16x8 af[2][4], bfr[2][2];
  #pragma unroll
  for (int ks = 0; ks < 2; ++ks)
    #pragma unroll
    for (int mi = 0; mi < 4; ++mi) {
      const int row = wrow + mi*16 + mcol;
      af[ks][mi] = *(const f16x8*)(S + row*64 + (((ks*4 + quad) ^ (row & 7)) * 8));
    }
  #pragma unroll
  for (int ks = 0; ks < 2; ++ks)
    #pragma unroll
    for (int ni = 0; ni < 2; ++ni) {
      const int nr = wcol + ni*16 + mcol;
      bfr[ks][ni] = *(const f16x8*)(w1T + nr*64 + ks*32 + quad*8);
    }

  f32x4 acc[4][2];
  #pragma unroll
  for (int mi = 0; mi < 4; ++mi)
    #pragma unroll
    for (int ni = 0; ni < 2; ++ni)
      acc[mi][ni] = (f32x4){0.f, 0.f, 0.f, 0.f};

  #pragma unroll
  for (int ks = 0; ks < 2; ++ks)
    #pragma unroll
    for (int mi = 0; mi < 4; ++mi)
      #pragma unroll
      for (int ni = 0; ni < 2; ++ni)
        acc[mi][ni] = __builtin_amdgcn_mfma_f32_16x16x32_f16(af[ks][mi], bfr[ks][ni], acc[mi][ni], 0, 0, 0);

  __syncthreads();   // done reading S; reuse as out tile

  float bb[2], wr0[2], wr1[2], wr2[2];
  #pragma unroll
  for (int ni = 0; ni < 2; ++ni) {
    const int col = wcol + ni*16 + mcol;
    bb[ni]  = b1[col];
    wr0[ni] = W1full[64*64 + col];
    wr1[ni] = W1full[65*64 + col];
    wr2[ni] = W1full[66*64 + col];
  }
  float s[2] = {0,0}, s2[2] = {0,0};
  #pragma unroll
  for (int mi = 0; mi < 4; ++mi) {
    #pragma unroll
    for (int j = 0; j < 4; ++j) {
      const int row = wrow + mi*16 + quad*4 + j;
      const float r0v = rl[row*3], r1v = rl[row*3+1], r2v = rl[row*3+2];
      #pragma unroll
      for (int ni = 0; ni < 2; ++ni) {
        const int col = wcol + ni*16 + mcol;
        const int g = col >> 3, o = col & 7;
        const float v = acc[mi][ni][j] + bb[ni] + r0v*wr0[ni] + r1v*wr1[ni] + r2v*wr2[ni];
        S[row*64 + ((g ^ (row & 7)) << 3) + o] = f2h(v);
        s[ni] += v; s2[ni] += v*v;
      }
    }
  }
  #pragma unroll
  for (int ni = 0; ni < 2; ++ni) {
    s[ni]  += __shfl_xor(s[ni], 16);  s[ni]  += __shfl_xor(s[ni], 32);
    s2[ni] += __shfl_xor(s2[ni], 16); s2[ni] += __shfl_xor(s2[ni], 32);
  }
  if (quad == 0) {
    const int rh = w >> 1;
    #pragma unroll
    for (int ni = 0; ni < 2; ++ni) {
      const int col = wcol + ni*16 + mcol;
      ps[rh*128 + col]      = s[ni];
      ps[rh*128 + 64 + col] = s2[ni];
    }
  }
  __syncthreads();

  #pragma unroll
  for (int i = 0; i < 4; ++i) {
    const int u = i*256 + t;
    const int row = u >> 3, gg = u & 7;
    *(uint4*)(zah + (size_t)(r0 + row)*64 + gg*8) =
        *(const uint4*)(S + row*64 + ((gg ^ (row & 7)) << 3));
  }
  if (t < 128) atomicAdd(&midA[t], ps[t] + ps[128 + t]);
}

// ---------------- conv2 layer2: fp16 MFMA + atomic BN-stats; reads fp16 za, writes fp16 zb ----------------
__global__ __launch_bounds__(256) void conv2_l2_mfma(
    const unsigned short* __restrict__ zah, const float* __restrict__ ss,
    const unsigned short* __restrict__ W2T, const float* __restrict__ b2,
    unsigned short* __restrict__ zhb, float* __restrict__ midB) {
  __shared__ unsigned short S[128*128];   // first 16KB: As; later: fp16 out tile
  __shared__ float ps[512];
  const int r0 = blockIdx.x * 128;
  const int t = threadIdx.x;
  const int lane = t & 63, w = t >> 6;
  const int quad = lane >> 4, mcol = lane & 15;

  {
    const int kb = t & 7, rr = t >> 3;
    float sc[8], sh[8];
    #pragma unroll
    for (int q = 0; q < 8; ++q) { sc[q] = ss[kb*8 + q]; sh[q] = ss[64 + kb*8 + q]; }
    #pragma unroll
    for (int it = 0; it < 4; ++it) {
      const int r = rr + it*32;
      union { uint4 v; unsigned short s[8]; } in;
      in.v = *(const uint4*)(zah + (size_t)(r0 + r)*64 + kb*8);
      union { unsigned short s[8]; uint4 v; } o;
      #pragma unroll
      for (int q = 0; q < 8; ++q)
        o.s[q] = f2h(fmaxf(h2f(in.s[q])*sc[q] + sh[q], 0.0f));
      *(uint4*)(S + r*64 + ((kb ^ (r & 7)) * 8)) = o.v;
    }
  }
  __syncthreads();

  const int wrow = (w >> 1) * 64;
  const int wcol = (w & 1) * 64;

  f16x8 af[2][4], bfr[2][4];
  #pragma unroll
  for (int ks = 0; ks < 2; ++ks)
    #pragma unroll
    for (int mi = 0; mi < 4; ++mi) {
      const int row = wrow + mi*16 + mcol;
      af[ks][mi] = *(const f16x8*)(S + row*64 + (((ks*4 + quad) ^ (row & 7)) * 8));
    }
  #pragma unroll
  for (int ks = 0; ks < 2; ++ks)
    #pragma unroll
    for (int ni = 0; ni < 4; ++ni) {
      const int nr = wcol + ni*16 + mcol;
      bfr[ks][ni] = *(const f16x8*)(W2T + nr*64 + ks*32 + quad*8);
    }

  f32x4 acc[4][4];
  #pragma unroll
  for (int mi = 0; mi < 4; ++mi)
    #pragma unroll
    for (int ni = 0; ni < 4; ++ni)
      acc[mi][ni] = (f32x4){0.f, 0.f, 0.f, 0.f};

  #pragma unroll
  for (int ks = 0; ks < 2; ++ks)
    #pragma unroll
    for (int mi = 0; mi < 4; ++mi)
      #pragma unroll
      for (int ni = 0; ni < 4; ++ni)
        acc[mi][ni] = __builtin_amdgcn_mfma_f32_16x16x32_f16(af[ks][mi], bfr[ks][ni], acc[mi][ni], 0, 0, 0);

  __syncthreads();

  float bb[4];
  #pragma unroll
  for (int ni = 0; ni < 4; ++ni) bb[ni] = b2[wcol + ni*16 + mcol];
  float s[4] = {0,0,0,0}, s2[4] = {0,0,0,0};
  #pragma unroll
  for (int mi = 0; mi < 4; ++mi) {
    #pragma unroll
    for (int ni = 0; ni < 4; ++ni) {
      const int col = wcol + ni*16 + mcol;
      const int g = col >> 3, o = col & 7;
      #pragma unroll
      for (int j = 0; j < 4; ++j) {
        const int row = wrow + mi*16 + quad*4 + j;
        const float v = acc[mi][ni][j] + bb[ni];
        S[row*128 + ((g ^ (row & 15)) << 3) + o] = f2h(v);
        s[ni] += v; s2[ni] += v*v;
      }
    }
  }
  #pragma unroll
  for (int ni = 0; ni < 4; ++ni) {
    s[ni]  += __shfl_xor(s[ni], 16);  s[ni]  += __shfl_xor(s[ni], 32);
    s2[ni] += __shfl_xor(s2[ni], 16); s2[ni] += __shfl_xor(s2[ni], 32);
  }
  if (quad == 0) {
    const int rh = w >> 1;
    #pragma unroll
    for (int ni = 0; ni < 4; ++ni) {
      const int col = wcol + ni*16 + mcol;
      ps[rh*256 + col]       = s[ni];
      ps[rh*256 + 128 + col] = s2[ni];
    }
  }
  __syncthreads();

  #pragma unroll
  for (int i = 0; i < 8; ++i) {
    const int u = i*256 + t;
    const int row = u >> 4, gg = u & 15;
    *(uint4*)(zhb + (size_t)(r0 + row)*128 + gg*8) =
        *(const uint4*)(S + row*128 + ((gg ^ (row & 15)) << 3));
  }
  atomicAdd(&midB[t], ps[t] + ps[256 + t]);
}

// ---------------- conv2 layer3 + full max fusion: 64x32 wave tiles (acc=32 AGPR), pm in LDS ----------------
// 2048 blocks: rb = bid & 1023 (128 rows), ch = bid >> 10 (512-col half).
// 8 chunks of 64 cols; per-chunk maxima fmax-accumulated into pm[2][512] (disjoint cols per wave).
__global__ __launch_bounds__(256, 3) void conv2_l3max_mfma(
    const unsigned short* __restrict__ zhb, const float* __restrict__ ss,
    const unsigned short* __restrict__ W3T,
    float* __restrict__ pmax2) {
  __shared__ unsigned short As[128*128];
  __shared__ float pm[1024];   // [rowhalf][512]
  const int rb = blockIdx.x & 1023, ch = blockIdx.x >> 10;
  const int r0 = rb * 128;
  const int t = threadIdx.x;
  const int lane = t & 63, w = t >> 6;
  const int quad = lane >> 4, mcol = lane & 15;

  #pragma unroll
  for (int i = 0; i < 4; ++i) pm[i*256 + t] = -INFINITY;

  // ---- stage A: relu(bn(zhb)) fp16 -> fp16, swizzled ----
  {
    const int kb = t & 15, rr = t >> 4;
    float sc[8], sh[8];
    #pragma unroll
    for (int q = 0; q < 8; ++q) { sc[q] = ss[kb*8 + q]; sh[q] = ss[128 + kb*8 + q]; }
    #pragma unroll
    for (int it = 0; it < 8; ++it) {
      const int r = rr + it*16;
      union { uint4 v; unsigned short s[8]; } in;
      in.v = *(const uint4*)(zhb + (size_t)(r0 + r)*128 + kb*8);
      union { unsigned short s[8]; uint4 v; } o;
      #pragma unroll
      for (int q = 0; q < 8; ++q)
        o.s[q] = f2h(fmaxf(h2f(in.s[q])*sc[q] + sh[q], 0.0f));
      *(uint4*)(As + r*128 + ((kb ^ (r & 7)) * 8)) = o.v;
    }
  }
  __syncthreads();

  const int wrow = (w >> 1) * 64;
  const int wncol = (w & 1) * 32;
  const int rh = w >> 1;

  #pragma unroll 1
  for (int chunk = 0; chunk < 8; ++chunk) {
    const int n0 = ch*512 + chunk*64;

    f32x4 acc[4][2];
    #pragma unroll
    for (int mi = 0; mi < 4; ++mi)
      #pragma unroll
      for (int ni = 0; ni < 2; ++ni)
        acc[mi][ni] = (f32x4){0.f, 0.f, 0.f, 0.f};

    #pragma unroll
    for (int ks = 0; ks < 4; ++ks) {
      f16x8 bfr[2], af[4];
      #pragma unroll
      for (int ni = 0; ni < 2; ++ni) {
        const int nr = n0 + wncol + ni*16 + mcol;
        bfr[ni] = *(const f16x8*)(W3T + (size_t)nr*128 + ks*32 + quad*8);
      }
      #pragma unroll
      for (int mi = 0; mi < 4; ++mi) {
        const int row = wrow + mi*16 + mcol;
        af[mi] = *(const f16x8*)(As + row*128 + (((ks*4 + quad) ^ (row & 7)) * 8));
      }
      #pragma unroll
      for (int mi = 0; mi < 4; ++mi)
        #pragma unroll
        for (int ni = 0; ni < 2; ++ni)
          acc[mi][ni] = __builtin_amdgcn_mfma_f32_16x16x32_f16(af[mi], bfr[ni], acc[mi][ni], 0, 0, 0);
    }

    // max over this wave's 64 rows per column; fmax-accumulate into pm
    #pragma unroll
    for (int ni = 0; ni < 2; ++ni) {
      float m4 = -INFINITY;
      #pragma unroll
      for (int mi = 0; mi < 4; ++mi) {
        f32x4 a = acc[mi][ni];
        m4 = fmaxf(m4, fmaxf(fmaxf(a[0], a[1]), fmaxf(a[2], a[3])));
      }
      m4 = fmaxf(m4, __shfl_xor(m4, 16));
      m4 = fmaxf(m4, __shfl_xor(m4, 32));
      if (quad == 0) {
        const int pc = rh*512 + chunk*64 + wncol + ni*16 + mcol;
        pm[pc] = fmaxf(pm[pc], m4);
      }
    }
  }
  __syncthreads();

  pmax2[(size_t)rb*1024 + ch*512 + t]       = fmaxf(pm[t], pm[512 + t]);
  pmax2[(size_t)rb*1024 + ch*512 + 256 + t] = fmaxf(pm[256 + t], pm[768 + t]);
}

// ---------------- final pool: max over 128 row-blocks per graph + b3 ----------------
__global__ __launch_bounds__(256) void pool_final_kernel(const float* __restrict__ pmax2,
    const float* __restrict__ b3, float* __restrict__ g) {
  const int b = blockIdx.x >> 2, q = blockIdx.x & 3;
  const int c = q*256 + threadIdx.x;
  const float* p = pmax2 + (size_t)b*128*1024 + c;
  float m = -INFINITY;
  for (int rb = 0; rb < 128; ++rb) m = fmaxf(m, p[(size_t)rb*1024]);
  g[b*1024 + c] = m + b3[c];
}

// ---------------- final linear (partials over c-quarters) ----------------
__global__ __launch_bounds__(256) void lin_kernel(const float* __restrict__ g,
    const float* __restrict__ W, float* __restrict__ zpart) {
  const int b = blockIdx.x >> 2, q = blockIdx.x & 3;
  const int o = threadIdx.x;
  const float* gb = g + b*1024 + q*256;
  const float* Wq = W + q*256*256;
  float acc = 0.0f;
  for (int c = 0; c < 256; ++c) acc += gb[c] * Wq[c*256 + o];
  zpart[blockIdx.x*256 + o] = acc;
}

// ---------------- final BN(8 rows) + relu ----------------
__global__ __launch_bounds__(256) void final_kernel(const float* __restrict__ zpart,
    const float* __restrict__ lb, const float* __restrict__ lg,
    const float* __restrict__ lbe, float* __restrict__ out) {
  const int o = threadIdx.x;
  float z[NB]; float s = 0.0f, s2 = 0.0f;
  #pragma unroll
  for (int b = 0; b < NB; ++b) {
    float v = lb[o];
    #pragma unroll
    for (int q = 0; q < 4; ++q) v += zpart[(b*4+q)*256 + o];
    z[b] = v; s += v; s2 += v*v;
  }
  const float mu  = s * 0.125f;
  const float var = s2 * 0.125f - mu*mu;
  const float inv = rsqrtf(var + 1e-5f);
  const float sc = lg[o]*inv, sh = lbe[o] - mu*sc;
  #pragma unroll
  for (int b = 0; b < NB; ++b) out[b*256 + o] = fmaxf(z[b]*sc + sh, 0.0f);
}

extern "C" void kernel_launch(void* const* d_in, const int* in_sizes, int n_in,
                              void* d_out, int out_size, void* d_ws, size_t ws_size,
                              hipStream_t stream) {
  const float* pos    = (const float*)d_in[0];
  const float* c1_W1  = (const float*)d_in[2];
  const float* c1_b1  = (const float*)d_in[3];
  const float* c1_g1  = (const float*)d_in[4];
  const float* c1_be1 = (const float*)d_in[5];
  const float* c1_W2  = (const float*)d_in[6];
  const float* c1_b2  = (const float*)d_in[7];
  const float* c2_W1  = (const float*)d_in[8];
  const float* c2_b1  = (const float*)d_in[9];
  const float* c2_g1  = (const float*)d_in[10];
  const float* c2_be1 = (const float*)d_in[11];
  const float* c2_W2  = (const float*)d_in[12];
  const float* c2_b2  = (const float*)d_in[13];
  const float* c2_g2  = (const float*)d_in[14];
  const float* c2_be2 = (const float*)d_in[15];
  const float* c2_W3  = (const float*)d_in[16];
  const float* c2_b3  = (const float*)d_in[17];
  const float* lin_W  = (const float*)d_in[18];
  const float* lin_b  = (const float*)d_in[19];
  const float* lin_g  = (const float*)d_in[20];
  const float* lin_be = (const float*)d_in[21];
  float* out = (float*)d_out;

  char* ws = (char*)d_ws;
  int*   idx     = (int*)  (ws + 0);                 // 512 KB
  float* rel     = (float*)(ws + 524288);            // 1.5 MB
  float* ss1     = (float*)(ws + 2097152);           // 128
  float* ssA     = (float*)(ws + 2097152 + 512);     // 128
  float* ssB     = (float*)(ws + 2097152 + 1024);    // 256
  float* zpart   = (float*)(ws + 2097152 + 2048);    // 8192
  float* gpool   = (float*)(ws + 2097152 + 2048 + 32768);          // 8192
  float* mid1    = (float*)(ws + 2164736);           // 128   } zeroed
  float* midA    = (float*)(ws + 2164736 + 512);     // 128   } by one
  float* midB    = (float*)(ws + 2164736 + 1024);    // 256   } memset
  unsigned short* W2T   = (unsigned short*)(ws + 2295808);  // 16 KB (conv2 W2)
  unsigned short* w1T   = (unsigned short*)(ws + 2312192);  // 8 KB  (conv2 W1 cols 0..63)
  unsigned short* W2c1T = (unsigned short*)(ws + 2320384);  // 8 KB  (conv1 W2)
  // bufA region (33.5 MB): z1h (fp16) -> zah (fp16) -> pmax2 (4 MB)
  unsigned short* z1h = (unsigned short*)(ws + 2426880);
  unsigned short* zah = (unsigned short*)(ws + 2426880);
  float* pmax2   = (float*)(ws + 2426880);
  unsigned short* x1h = (unsigned short*)(ws + 35981312);  // 1 MB fp16
  unsigned short* zhb = (unsigned short*)(ws + 38078464);  // 33.5 MB fp16 zb
  unsigned short* W3T = (unsigned short*)(ws + 71632896);  // 256 KB

  const float invPK = 1.0f / (float)PK;

  hipMemsetAsync(ws + 2164736, 0, 2048, stream);   // zero mid1/midA/midB
  wprep_kernel<<<140, 256, 0, stream>>>(c2_W3, c2_W2, c2_W1, c1_W2, W3T, W2T, w1T, W2c1T);
  knn_kernel<<<PTS/4, 256, 0, stream>>>(pos, idx, rel);
  conv1_l1_kernel<<<PK/64, 256, 0, stream>>>(pos, idx, rel, c1_W1, c1_b1, z1h, mid1);
  stats_final_kernel<<<1, 256, 0, stream>>>(mid1, 1, 64, invPK, c1_g1, c1_be1, ss1);
  conv1_l2max_mfma<<<PK/128, 256, 0, stream>>>(z1h, ss1, W2c1T, c1_b2, x1h);
  conv2_l1_mfma<<<PK/128, 256, 0, stream>>>(x1h, idx, rel, w1T, c2_W1, c2_b1, zah, midA);
  stats_final_kernel<<<1, 256, 0, stream>>>(midA, 1, 64, invPK, c2_g1, c2_be1, ssA);
  conv2_l2_mfma<<<PK/128, 256, 0, stream>>>(zah, ssA, W2T, c2_b2, zhb, midB);
  stats_final_kernel<<<1, 256, 0, stream>>>(midB, 1, 128, invPK, c2_g2, c2_be2, ssB);
  conv2_l3max_mfma<<<PK/64, 256, 0, stream>>>(zhb, ssB, W3T, pmax2);
  pool_final_kernel<<<NB*4, 256, 0, stream>>>(pmax2, c2_b3, gpool);
  lin_kernel<<<32, 256, 0, stream>>>(gpool, lin_W, zpart);
  final_kernel<<<1, 256, 0, stream>>>(zpart, lin_b, lin_g, lin_be, out);
}